// Round 8
// baseline (150.811 us; speedup 1.0000x reference)
//
#include <hip/hip_runtime.h>

#define R_DIM 2048
#define O_DIM 32
#define I_DIM 16
#define B_DIM 64
#define BB 16   // batch rows per block

typedef _Float16 half8  __attribute__((ext_vector_type(8)));
typedef float    f32x4  __attribute__((ext_vector_type(4)));

struct SplitH { half8 h1, h2; };

// 2-way fp16 split of 8 consecutive fp32 via HW packed-cvt (RTZ):
// x = h1 + h2 + O(2^-22 * x).
__device__ __forceinline__ SplitH splitf16x8(const float* __restrict__ p) {
    float f[8];
    *(float4*)(f)     = *(const float4*)(p);
    *(float4*)(f + 4) = *(const float4*)(p + 4);
    SplitH r;
    #pragma unroll
    for (int j = 0; j < 4; ++j) {
        const auto a = __builtin_amdgcn_cvt_pkrtz(f[2*j], f[2*j+1]);   // __fp16 x2
        const float r0 = f[2*j]     - (float)a[0];
        const float r1 = f[2*j + 1] - (float)a[1];
        const auto c = __builtin_amdgcn_cvt_pkrtz(r0, r1);
        r.h1[2*j] = (_Float16)a[0]; r.h1[2*j+1] = (_Float16)a[1];
        r.h2[2*j] = (_Float16)c[0]; r.h2[2*j+1] = (_Float16)c[1];
    }
    return r;
}

// DPP helpers — all stay on the VALU pipe (no DS traffic).
template<int CTRL>
__device__ __forceinline__ float dpp_mv(float v) {
    int t = __builtin_amdgcn_update_dpp(0, __float_as_int(v), CTRL, 0xf, 0xf, true);
    return __int_as_float(t);
}
__device__ __forceinline__ float row16_sum(float v) {
    v += dpp_mv<0xB1>(v);    // quad_perm xor1
    v += dpp_mv<0x4E>(v);    // quad_perm xor2
    v += dpp_mv<0x124>(v);   // row_ror:4
    v += dpp_mv<0x128>(v);   // row_ror:8
    return v;
}
__device__ __forceinline__ float row16_max(float v) {
    v = fmaxf(v, dpp_mv<0xB1>(v));
    v = fmaxf(v, dpp_mv<0x4E>(v));
    v = fmaxf(v, dpp_mv<0x124>(v));
    v = fmaxf(v, dpp_mv<0x128>(v));
    return v;
}
// row_ror:1 — dst[n] = src[(n-1)&15] (data moves toward higher lanes)
__device__ __forceinline__ float ror1(float v) { return dpp_mv<0x121>(v); }

// XOR bank swizzle: phase-1 C-scatter 2-way (free); phase-2 b64 reads at the
// structural 512B/instr floor.
__device__ __forceinline__ int swaddr(int b, int col) {
    return b * 512 + (col ^ (((b ^ (b >> 2)) & 3) << 3));
}

// Block: 256 threads = 4 waves; one (r, 16-batch slice); 32 KB LDS -> 5 blocks/CU.
// Phase 1: u_hat[16b x 512n] via 3-term fp16-split MFMA; wave w owns n-tiles 8w..8w+7.
// Phase 2 (barrier-free, all 256 threads): thread=(b=tid>>4, j=tid&15) owns
//   o={2j,2j+1}. Routing state DISTRIBUTED: lane j holds logit bv[c=j].
//   u2[k] = u_hat[c=(j-k)&15][o-pair j]. Agreement + softmax-weighted sums run
//   as row_ror:1 systolic rotations (static register indices, runtime LDS addrs).
__global__ __launch_bounds__(256, 5)
void capsule_routing_kernel(const float* __restrict__ x,
                            const float* __restrict__ W,
                            float* __restrict__ out) {
    __shared__ float u_lds[BB * 512];   // 32 KB

    const int tid = threadIdx.x;
    const int bid = blockIdx.x;
    const int r   = bid >> 2;
    const int b0  = (bid & 3) * BB;

    // ---------------- Phase 1: fp16-split MFMA u_hat ----------------
    {
        const int lane = tid & 63;
        const int w    = tid >> 6;     // wave 0..3 -> n-tiles 8w..8w+7
        const int q    = lane >> 4;    // k-quad (2,3 = zero pad)
        const int np   = lane & 15;    // m (batch) for A / n-col for B

        const half8 z8 = {0,0,0,0,0,0,0,0};
        SplitH as; as.h1 = z8; as.h2 = z8;
        if (q < 2)
            as = splitf16x8(x + ((size_t)(b0 + np) * R_DIM + r) * I_DIM + q * 8);

        const f32x4 zero4 = {0.f, 0.f, 0.f, 0.f};
        #pragma unroll
        for (int t = 0; t < 8; ++t) {
            const int ntile = w * 8 + t;
            SplitH bs; bs.h1 = z8; bs.h2 = z8;
            if (q < 2)
                bs = splitf16x8(W + ((size_t)r * 512 + ntile * 16 + np) * I_DIM + q * 8);

            f32x4 a = __builtin_amdgcn_mfma_f32_16x16x32_f16(as.h2, bs.h1, zero4, 0, 0, 0);
            a = __builtin_amdgcn_mfma_f32_16x16x32_f16(as.h1, bs.h2, a, 0, 0, 0);
            a = __builtin_amdgcn_mfma_f32_16x16x32_f16(as.h1, bs.h1, a, 0, 0, 0);

            const int col = ntile * 16 + np;
            #pragma unroll
            for (int reg = 0; reg < 4; ++reg)
                u_lds[swaddr(q * 4 + reg, col)] = a[reg];
        }
    }
    __syncthreads();

    // ---------------- Phase 2: systolic dynamic routing ----------------
    {
        const int b = tid >> 4;    // 0..15 local batch (one DPP row per b)
        const int j = tid & 15;    // o-pair index / owner of logit c=j

        // u2[2k],u2[2k+1] = u_hat[c=(j-k)&15][o=2j,2j+1]
        float u2[32];
        #pragma unroll
        for (int k = 0; k < 16; ++k) {
            const int c = (j - k) & 15;
            const float2 v2 = *(const float2*)&u_lds[swaddr(b, c * 32 + 2 * j)];
            u2[2 * k]     = v2.x;
            u2[2 * k + 1] = v2.y;
        }

        float bvv = 0.0f;          // logit for c=j (distributed)
        float s0 = 0.f, s1 = 0.f, g = 0.f;

        #pragma unroll
        for (int it = 0; it < 3; ++it) {
            if (it == 0) {
                // softmax(0) = 1/16 uniform; all c's are in u2 locally
                s0 = 0.f; s1 = 0.f;
                #pragma unroll
                for (int k = 0; k < 16; ++k) { s0 += u2[2*k]; s1 += u2[2*k+1]; }
                s0 *= 0.0625f; s1 *= 0.0625f;
            } else {
                // softmax at lane c: 1 exp/thread
                const float m = row16_max(bvv);
                const float e = __expf(bvv - m);
                const float Z = row16_sum(e);
                float wr = e * __builtin_amdgcn_rcpf(Z);   // w_c at lane c
                // s_j = sum_c w_c * u[c][o]; rotate w: after k ror1's lane j holds w_{j-k}
                s0 = 0.f; s1 = 0.f;
                #pragma unroll
                for (int k = 0; k < 16; ++k) {
                    if (k > 0) wr = ror1(wr);
                    s0 = fmaf(wr, u2[2*k],     s0);
                    s1 = fmaf(wr, u2[2*k + 1], s1);
                }
            }

            // g = ||s|| / (1 + ||s||^2), norm over 32 o's (16 j-lanes x 2)
            const float nn = row16_sum(s0 * s0 + s1 * s1);
            g = sqrtf(nn) * __builtin_amdgcn_rcpf(1.0f + nn);

            if (it < 2) {
                // t[c] = sum_j u[c][2j]s0_j + u[c][2j+1]s1_j via rotating accumulator:
                // partial for c sits at lane (c+k) at step k; lane j handles c=(j-k)=u2[k]
                float acc = 0.f;
                #pragma unroll
                for (int k = 0; k < 16; ++k) {
                    if (k > 0) acc = ror1(acc);
                    acc = fmaf(u2[2*k],     s0, acc);
                    acc = fmaf(u2[2*k + 1], s1, acc);
                }
                acc = ror1(acc);           // t[c] lands at lane c
                bvv = fmaf(g, acc, bvv);   // b[c] += g * t[c]
            }
        }

        *(float2*)(out + ((size_t)(b0 + b) * R_DIM + r) * O_DIM + 2 * j)
            = make_float2(g * s0, g * s1);
    }
}

extern "C" void kernel_launch(void* const* d_in, const int* in_sizes, int n_in,
                              void* d_out, int out_size, void* d_ws, size_t ws_size,
                              hipStream_t stream) {
    const float* x   = (const float*)d_in[0];   // [64, 2048, 16]
    const float* W   = (const float*)d_in[1];   // [2048, 16, 32, 16]
    float*       out = (float*)d_out;           // [64, 2048, 32]

    dim3 grid(R_DIM * (B_DIM / BB));            // 8192 blocks
    dim3 block(256);
    hipLaunchKernelGGL(capsule_routing_kernel, grid, block, 0, stream, x, W, out);
}

// Round 9
// 138.338 us; speedup vs baseline: 1.0902x; 1.0902x over previous
//
#include <hip/hip_runtime.h>

#define R_DIM 2048
#define O_DIM 32
#define I_DIM 16
#define B_DIM 64
#define BB 16   // batch rows per block

typedef _Float16 half8  __attribute__((ext_vector_type(8)));
typedef float    f32x4  __attribute__((ext_vector_type(4)));

struct SplitH { half8 h1, h2; };

// 2-way fp16 split of 8 consecutive fp32 via HW packed-cvt (RTZ):
// x = h1 + h2 + O(2^-22 * x).
__device__ __forceinline__ SplitH splitf16x8(const float* __restrict__ p) {
    float f[8];
    *(float4*)(f)     = *(const float4*)(p);
    *(float4*)(f + 4) = *(const float4*)(p + 4);
    SplitH r;
    #pragma unroll
    for (int j = 0; j < 4; ++j) {
        const auto a = __builtin_amdgcn_cvt_pkrtz(f[2*j], f[2*j+1]);   // __fp16 x2
        const float r0 = f[2*j]     - (float)a[0];
        const float r1 = f[2*j + 1] - (float)a[1];
        const auto c = __builtin_amdgcn_cvt_pkrtz(r0, r1);
        r.h1[2*j] = (_Float16)a[0]; r.h1[2*j+1] = (_Float16)a[1];
        r.h2[2*j] = (_Float16)c[0]; r.h2[2*j+1] = (_Float16)c[1];
    }
    return r;
}

// DPP helpers — all stay on the VALU pipe (no DS traffic).
template<int CTRL>
__device__ __forceinline__ float dpp_mv(float v) {
    int t = __builtin_amdgcn_update_dpp(0, __float_as_int(v), CTRL, 0xf, 0xf, true);
    return __int_as_float(t);
}
__device__ __forceinline__ float row16_sum(float v) {
    v += dpp_mv<0xB1>(v);    // quad_perm xor1
    v += dpp_mv<0x4E>(v);    // quad_perm xor2
    v += dpp_mv<0x124>(v);   // row_ror:4
    v += dpp_mv<0x128>(v);   // row_ror:8
    return v;
}
__device__ __forceinline__ float row16_max(float v) {
    v = fmaxf(v, dpp_mv<0xB1>(v));
    v = fmaxf(v, dpp_mv<0x4E>(v));
    v = fmaxf(v, dpp_mv<0x124>(v));
    v = fmaxf(v, dpp_mv<0x128>(v));
    return v;
}
// row_ror:1 — dst[n] = src[(n-1)&15]
__device__ __forceinline__ float ror1(float v) { return dpp_mv<0x121>(v); }

// XOR bank swizzle: phase-1 C-scatter 2-way (free); phase-2 b64 reads at the
// structural 512B/instr floor.
__device__ __forceinline__ int swaddr(int b, int col) {
    return b * 512 + (col ^ (((b ^ (b >> 2)) & 3) << 3));
}

// Block: 512 threads = 8 waves; one (r, 16-batch slice); 32 KB LDS ->
// 4 blocks/CU = 32 waves/CU cap (the 256-thr version capped at 16 — R8's stall).
// Phase 1 (all 8 waves): u_hat[16b x 512n] via 3-term fp16-split MFMA;
//   wave w owns n-tiles 4w..4w+3.
// Phase 2 (barrier-free, first 256 lanes; waves 4-7 retire): thread=(b,j) owns
//   o={2j,2j+1}; lane j holds logit bv[c=j]; systolic row_ror:1 rotations.
__global__ __launch_bounds__(512, 8)
void capsule_routing_kernel(const float* __restrict__ x,
                            const float* __restrict__ W,
                            float* __restrict__ out) {
    __shared__ float u_lds[BB * 512];   // 32 KB

    const int tid = threadIdx.x;
    const int bid = blockIdx.x;
    const int r   = bid >> 2;
    const int b0  = (bid & 3) * BB;

    // ---------------- Phase 1: fp16-split MFMA u_hat ----------------
    {
        const int lane = tid & 63;
        const int w    = tid >> 6;     // wave 0..7 -> n-tiles 4w..4w+3
        const int q    = lane >> 4;    // k-quad (2,3 = zero pad)
        const int np   = lane & 15;    // m (batch) for A / n-col for B

        const half8 z8 = {0,0,0,0,0,0,0,0};
        SplitH as; as.h1 = z8; as.h2 = z8;
        if (q < 2)
            as = splitf16x8(x + ((size_t)(b0 + np) * R_DIM + r) * I_DIM + q * 8);

        const f32x4 zero4 = {0.f, 0.f, 0.f, 0.f};
        #pragma unroll
        for (int t = 0; t < 4; ++t) {
            const int ntile = w * 4 + t;
            SplitH bs; bs.h1 = z8; bs.h2 = z8;
            if (q < 2)
                bs = splitf16x8(W + ((size_t)r * 512 + ntile * 16 + np) * I_DIM + q * 8);

            f32x4 a = __builtin_amdgcn_mfma_f32_16x16x32_f16(as.h2, bs.h1, zero4, 0, 0, 0);
            a = __builtin_amdgcn_mfma_f32_16x16x32_f16(as.h1, bs.h2, a, 0, 0, 0);
            a = __builtin_amdgcn_mfma_f32_16x16x32_f16(as.h1, bs.h1, a, 0, 0, 0);

            const int col = ntile * 16 + np;
            #pragma unroll
            for (int reg = 0; reg < 4; ++reg)
                u_lds[swaddr(q * 4 + reg, col)] = a[reg];
        }
    }
    __syncthreads();

    // ---------------- Phase 2: systolic dynamic routing (lanes 0-255) ----------
    if (tid < 256) {
        const int b = tid >> 4;    // 0..15 local batch (one DPP row per b)
        const int j = tid & 15;    // o-pair index / owner of logit c=j

        // u2[2k],u2[2k+1] = u_hat[c=(j-k)&15][o=2j,2j+1]
        float u2[32];
        #pragma unroll
        for (int k = 0; k < 16; ++k) {
            const int c = (j - k) & 15;
            const float2 v2 = *(const float2*)&u_lds[swaddr(b, c * 32 + 2 * j)];
            u2[2 * k]     = v2.x;
            u2[2 * k + 1] = v2.y;
        }

        float bvv = 0.0f;          // logit for c=j (distributed)
        float s0 = 0.f, s1 = 0.f, g = 0.f;

        #pragma unroll
        for (int it = 0; it < 3; ++it) {
            if (it == 0) {
                s0 = 0.f; s1 = 0.f;
                #pragma unroll
                for (int k = 0; k < 16; ++k) { s0 += u2[2*k]; s1 += u2[2*k+1]; }
                s0 *= 0.0625f; s1 *= 0.0625f;
            } else {
                // softmax at lane c: 1 exp/thread
                const float m = row16_max(bvv);
                const float e = __expf(bvv - m);
                const float Z = row16_sum(e);
                float wr = e * __builtin_amdgcn_rcpf(Z);   // w_c at lane c
                // s_j = sum_c w_c * u[c][o]; after k ror1's lane j holds w_{j-k}
                s0 = 0.f; s1 = 0.f;
                #pragma unroll
                for (int k = 0; k < 16; ++k) {
                    if (k > 0) wr = ror1(wr);
                    s0 = fmaf(wr, u2[2*k],     s0);
                    s1 = fmaf(wr, u2[2*k + 1], s1);
                }
            }

            // g = ||s|| / (1 + ||s||^2), norm over 32 o's (16 j-lanes x 2)
            const float nn = row16_sum(s0 * s0 + s1 * s1);
            g = sqrtf(nn) * __builtin_amdgcn_rcpf(1.0f + nn);

            if (it < 2) {
                // t[c] via rotating accumulator; t[c] lands at lane c
                float acc = 0.f;
                #pragma unroll
                for (int k = 0; k < 16; ++k) {
                    if (k > 0) acc = ror1(acc);
                    acc = fmaf(u2[2*k],     s0, acc);
                    acc = fmaf(u2[2*k + 1], s1, acc);
                }
                acc = ror1(acc);
                bvv = fmaf(g, acc, bvv);   // b[c] += g * t[c]
            }
        }

        *(float2*)(out + ((size_t)(b0 + b) * R_DIM + r) * O_DIM + 2 * j)
            = make_float2(g * s0, g * s1);
    }
}

extern "C" void kernel_launch(void* const* d_in, const int* in_sizes, int n_in,
                              void* d_out, int out_size, void* d_ws, size_t ws_size,
                              hipStream_t stream) {
    const float* x   = (const float*)d_in[0];   // [64, 2048, 16]
    const float* W   = (const float*)d_in[1];   // [2048, 16, 32, 16]
    float*       out = (float*)d_out;           // [64, 2048, 32]

    dim3 grid(R_DIM * (B_DIM / BB));            // 8192 blocks
    dim3 block(512);
    hipLaunchKernelGGL(capsule_routing_kernel, grid, block, 0, stream, x, W, out);
}